// Round 14
// baseline (75.098 us; speedup 1.0000x reference)
//
#include <hip/hip_runtime.h>
#include <hip/hip_fp16.h>
#include <cmath>

#define NBINS   84
#define NFRAMES 256
#define HOP     1024
#define NB      8            // nb_samples * nb_channels
#define KP      960          // padded K (f16 columns of A / rows of B)
#define KPQ     (KP/8)       // 120 quads (4 cos/sin pairs) per row
#define GBLK    278          // number of 1024-sample output blocks
#define MROWS   (GBLK*NB)    // 2224 real rows
#define MPAD    2240         // 70*32
#define SD      23           // d-slices: max ceil(L/1024)

// builder regions (blocks of 256 threads)
#define BT_BLOCKS  480                      // 1024 r x 120 quads / 256
#define A_BLOCKS   (MPAD*KPQ/256)           // 1050
#define S_BLOCKS   92                       // 23*1024/256
#define ALL_BLOCKS (BT_BLOCKS + A_BLOCKS + S_BLOCKS)

typedef _Float16 f16x8 __attribute__((ext_vector_type(8)));
typedef float    f32x4 __attribute__((ext_vector_type(4)));

struct alignas(16) CqtArgs {
    unsigned short ct[KP];      // FIRST member, 16B-aligned: col -> k|d<<7|c<<12; 0xFFFF pad
    int   wl[NBINS];            // per-bin window length (descending)
    float omega[NBINS];         // 2*pi*f/SR
    float invL[NBINS];          // 1/wl
    int   Ktot;
};

// ---------------- fused builder: Bt + A + S (one kernel) ---------------------
__global__ __launch_bounds__(256)
void build_all(unsigned short* __restrict__ Am, unsigned short* __restrict__ Bt,
               float* __restrict__ S, const float2* __restrict__ X2, CqtArgs a) {
    const int blk = blockIdx.x;
    const int tid = threadIdx.x;
    const float TWOPI = 6.28318530717958647692f;

    if (blk < BT_BLOCKS) {
        // Bt[r][2j]=cos(w_k t)*hann, [2j+1]=sin(w_k t)*hann; t=1024d+r; 4 pairs/thread
        const int idx  = blk * 256 + tid;        // < 1024*120
        const int r    = idx / KPQ;
        const int quad = idx - r * KPQ;
        const uint4 rr = *(const uint4*)(&a.ct[8 * quad]);
        const unsigned int recs[4] = { rr.x & 0xFFFFu, rr.y & 0xFFFFu,
                                       rr.z & 0xFFFFu, rr.w & 0xFFFFu };
        f16x8 v;
#pragma unroll
        for (int jj = 0; jj < 4; ++jj) {
            float vc = 0.f, vs = 0.f;
            const unsigned int rec = recs[jj];
            if (rec != 0xFFFFu) {
                const int k = rec & 0x7F, d = (rec >> 7) & 0x1F;
                const int t = (d << 10) + r;
                if (t < a.wl[k]) {
                    const float tf = (float)t;
                    const float w  = 0.5f - 0.5f * cosf(TWOPI * tf * a.invL[k]);
                    float s, c;
                    sincosf(a.omega[k] * tf, &s, &c);
                    vc = c * w; vs = s * w;
                }
            }
            v[2 * jj]     = (_Float16)vc;
            v[2 * jj + 1] = (_Float16)vs;
        }
        *(f16x8*)(Bt + (size_t)r * KP + 8 * quad) = v;
    } else if (blk < BT_BLOCKS + A_BLOCKS) {
        // A[row=(g*8+b)][2j]=Re X[b,k,g-d], [2j+1]=-Im X[b,k,g-d]; 4 pairs/thread
        const int idx  = (blk - BT_BLOCKS) * 256 + tid;   // < 2240*120
        const int row  = idx / KPQ;
        const int quad = idx - row * KPQ;
        const int g = row >> 3, b = row & 7;
        const bool rowok = (row < MROWS);
        const uint4 rr = *(const uint4*)(&a.ct[8 * quad]);
        const unsigned int recs[4] = { rr.x & 0xFFFFu, rr.y & 0xFFFFu,
                                       rr.z & 0xFFFFu, rr.w & 0xFFFFu };
        f16x8 v;
#pragma unroll
        for (int jj = 0; jj < 4; ++jj) {
            float re = 0.f, nim = 0.f;
            const unsigned int rec = recs[jj];
            const int k = rec & 0x7F, d = (rec >> 7) & 0x1F;
            const int f = g - d;
            if (rowok && rec != 0xFFFFu && f >= 0 && f < NFRAMES) {
                const float2 x = X2[((size_t)b * NBINS + k) * NFRAMES + f];
                re = x.x; nim = -x.y;
            }
            v[2 * jj]     = (_Float16)re;
            v[2 * jj + 1] = (_Float16)nim;
        }
        *(f16x8*)(Am + (size_t)row * KP + 8 * quad) = v;
    } else {
        // S[t] = sum_k [t < wl_k] hann_k(t)^2 ; wl descending -> break at first fail
        const int t = (blk - BT_BLOCKS - A_BLOCKS) * 256 + tid;   // t < 23552
        float sum = 0.f;
        for (int k = 0; k < NBINS; ++k) {
            if (t >= a.wl[k]) break;
            const float w = 0.5f - 0.5f * cosf(TWOPI * (float)t * a.invL[k]);
            sum += w * w;
        }
        S[t] = sum;
    }
}

// inverse norm: direct positive-term sum over d = max(0,g-255) .. min(g,22)
__device__ __forceinline__ float inv_norm(const float* __restrict__ S, int g, int ncol) {
    if (g >= GBLK) return 1.0f;
    const int lo = (g > NFRAMES - 1) ? (g - (NFRAMES - 1)) : 0;
    const int hi = g < (SD - 1) ? g : (SD - 1);
    float s = 0.f;
    for (int d = lo; d <= hi; ++d) s += S[(d << 10) + ncol];
    return (s > 1e-10f) ? 1.0f / s : 1.0f;
}

// GEMM, no LDS: each wave computes an independent 32x32 tile of C = A * Bt^T,
// MFMA fragments loaded DIRECTLY from L2-resident A/Bt (16B per lane, 64B/row
// per window, consecutive windows stream consecutive 64B). Zero barriers ->
// compiler software-pipelines loads; waves in a block share A rows (L1 reuse).
// 560 blocks x 4 waves; bijective XCD swizzle: each XCD owns one bn-slab of B.
__global__ __launch_bounds__(256)
void gemm_icqt(const unsigned short* __restrict__ Am, const unsigned short* __restrict__ Bt,
               const float* __restrict__ S, float* __restrict__ out, int length) {
    const int tid = threadIdx.x;
    const int l   = tid & 63;
    const int w   = tid >> 6;
    // XCD swizzle: 560 = 8 * 70, bijective
    const int swz = (blockIdx.x & 7) * 70 + (blockIdx.x >> 3);
    const int bm  = swz % 70;              // 32-row panel
    const int bn  = swz / 70;              // 128-col slab; wave w owns 32 cols
    const int m0  = bm * 32;
    const int n0  = bn * 128 + w * 32;

    const int lr = l & 15;                 // fragment row
    const int kq = l >> 4;                 // fragment k-chunk (16B) in window

    const char* pa0 = (const char*)Am + (size_t)(m0 + lr) * (KP * 2) + kq * 16;
    const char* pa1 = pa0 + (size_t)16 * KP * 2;
    const char* pb0 = (const char*)Bt + (size_t)(n0 + lr) * (KP * 2) + kq * 16;
    const char* pb1 = pb0 + (size_t)16 * KP * 2;

    f32x4 acc00 = {0.f,0.f,0.f,0.f}, acc01 = {0.f,0.f,0.f,0.f};
    f32x4 acc10 = {0.f,0.f,0.f,0.f}, acc11 = {0.f,0.f,0.f,0.f};

#pragma unroll 3
    for (int kw = 0; kw < KP / 32; ++kw) {         // 30 windows of K=32
        const int off = kw * 64;                   // 64B per row per window
        f16x8 a0 = *(const f16x8*)(pa0 + off);
        f16x8 a1 = *(const f16x8*)(pa1 + off);
        f16x8 b0 = *(const f16x8*)(pb0 + off);
        f16x8 b1 = *(const f16x8*)(pb1 + off);
        acc00 = __builtin_amdgcn_mfma_f32_16x16x32_f16(a0, b0, acc00, 0, 0, 0);
        acc01 = __builtin_amdgcn_mfma_f32_16x16x32_f16(a0, b1, acc01, 0, 0, 0);
        acc10 = __builtin_amdgcn_mfma_f32_16x16x32_f16(a1, b0, acc10, 0, 0, 0);
        acc11 = __builtin_amdgcn_mfma_f32_16x16x32_f16(a1, b1, acc11, 0, 0, 0);
    }

    // epilogue: C/D layout col=lr, row=kq*4+reg. Lane spans 2 g's x 2 ncols.
    const int ncol0 = n0 + lr;
    const int ncol1 = ncol0 + 16;
    const int g0    = (m0 >> 3) + (kq >> 1);
    const float inv00 = inv_norm(S, g0,     ncol0);
    const float inv01 = inv_norm(S, g0,     ncol1);
    const float inv10 = inv_norm(S, g0 + 2, ncol0);
    const float inv11 = inv_norm(S, g0 + 2, ncol1);

#pragma unroll
    for (int mi = 0; mi < 2; ++mi) {
#pragma unroll
        for (int ni = 0; ni < 2; ++ni) {
            const f32x4 v    = (mi == 0) ? ((ni == 0) ? acc00 : acc01)
                                         : ((ni == 0) ? acc10 : acc11);
            const float invv = (mi == 0) ? ((ni == 0) ? inv00 : inv01)
                                         : ((ni == 0) ? inv10 : inv11);
            const int ncol = (ni == 0) ? ncol0 : ncol1;
#pragma unroll
            for (int reg = 0; reg < 4; ++reg) {
                const int mrow = m0 + mi * 16 + kq * 4 + reg;
                if (mrow < MROWS) {
                    const int g = mrow >> 3, b = mrow & 7;
                    const int p = (g << 10) + ncol;
                    if (p < length)
                        out[(size_t)b * length + p] = v[reg] * invv;
                }
            }
        }
    }
}

// Last-resort fallback (ws too small): on-the-fly trig gather.
__global__ void icqt_gather_fallback(const float* __restrict__ X, float* __restrict__ out,
                                     CqtArgs a, int length) {
    const int p = blockIdx.x * blockDim.x + threadIdx.x;
    if (p >= length) return;
    float acc[NB];
#pragma unroll
    for (int b = 0; b < NB; ++b) acc[b] = 0.0f;
    float nrm = 0.0f;
    int fhi = p >> 10;
    if (fhi > NFRAMES - 1) fhi = NFRAMES - 1;
    const float2* X2 = reinterpret_cast<const float2*>(X);
    for (int k = 0; k < NBINS; ++k) {
        const int L = a.wl[k];
        int flo = (p - L + HOP) >> 10;
        if (flo < 0) flo = 0;
        for (int f = flo; f <= fhi; ++f) {
            const int t = p - (f << 10);
            if (t < L) {
                float tf = (float)t;
                float ang = a.omega[k] * tf;
                float s = sinf(ang), c = cosf(ang);
                float w = 0.5f - 0.5f * cosf(6.28318530717958647692f * tf * a.invL[k]);
                float bre = c * w, bim = s * w;
                nrm += w * w;
                const int base = k * NFRAMES + f;
#pragma unroll
                for (int b = 0; b < NB; ++b) {
                    float2 cv = X2[(size_t)b * (NBINS * NFRAMES) + base];
                    acc[b] += cv.x * bre - cv.y * bim;
                }
            }
        }
    }
    const float inv = 1.0f / ((nrm > 1e-10f) ? nrm : 1.0f);
#pragma unroll
    for (int b = 0; b < NB; ++b)
        out[(size_t)b * length + p] = acc[b] * inv;
}

extern "C" void kernel_launch(void* const* d_in, const int* in_sizes, int n_in,
                              void* d_out, int out_size, void* d_ws, size_t ws_size,
                              hipStream_t stream) {
    // Host geometry (deterministic; np.round = banker's via nearbyint)
    CqtArgs a;
    int cb[NBINS];
    const double SR = 44100.0;
    const double Q  = 1.0 / (std::exp2(1.0 / 12.0) - 1.0);
    int Ktot = 0;
    for (int k = 0; k < NBINS; ++k) {
        double f = 32.7 * std::exp2((double)k / 12.0);
        int L = (int)std::nearbyint(Q * SR / f);
        a.wl[k]    = L;
        cb[k]      = Ktot;
        a.omega[k] = (float)(2.0 * 3.14159265358979323846 * f / SR);
        a.invL[k]  = (float)(1.0 / (double)L);
        Ktot += 2 * ((L + 1023) / 1024);
    }
    a.Ktot = Ktot;
    for (int col = 0; col < KP; ++col) a.ct[col] = 0xFFFF;
    if (Ktot <= KP) {
        for (int k = 0; k < NBINS; ++k) {
            const int D2 = 2 * ((a.wl[k] + 1023) / 1024);
            for (int j = 0; j < D2; ++j)
                a.ct[cb[k] + j] = (unsigned short)(k | ((j >> 1) << 7) | ((j & 1) << 12));
        }
    }

    const int length = out_size / NB;            // 283800
    const float* X = (const float*)d_in[0];
    float* out     = (float*)d_out;

    // ws layout: [ A f16 MPADxKP ][ Bt f16 1024xKP ][ S f32 23*1024 ]
    const size_t offA = 0;
    const size_t szA  = (size_t)MPAD * KP * 2;           // 4,300,800
    const size_t offB = offA + szA;
    const size_t szB  = (size_t)1024 * KP * 2;           // 1,966,080
    const size_t offS = offB + szB;
    const size_t szS  = (size_t)SD * 1024 * 4;           //    94,208
    const size_t need = offS + szS;

    if (Ktot > KP || a.wl[0] > SD * 1024 || ws_size < need) {
        const int blocks = (length + 255) / 256;
        icqt_gather_fallback<<<blocks, 256, 0, stream>>>(X, out, a, length);
        return;
    }

    unsigned short* Am = (unsigned short*)((char*)d_ws + offA);
    unsigned short* Bt = (unsigned short*)((char*)d_ws + offB);
    float*          S  = (float*)((char*)d_ws + offS);

    build_all<<<dim3(ALL_BLOCKS), 256, 0, stream>>>(Am, Bt, S, (const float2*)X, a);
    gemm_icqt<<<dim3(560), 256, 0, stream>>>(Am, Bt, S, out, length);
}

// Round 15
// 47.062 us; speedup vs baseline: 1.5957x; 1.5957x over previous
//
#include <hip/hip_runtime.h>
#include <hip/hip_fp16.h>
#include <cmath>

#define NBINS   84
#define NFRAMES 256
#define HOP     1024
#define NB      8            // nb_samples * nb_channels
#define KP      960          // padded K (f16 columns of A / rows of B)
#define KPH     (KP/2)       // 480 cos/sin column pairs
#define GBLK    278          // number of 1024-sample output blocks
#define MROWS   (GBLK*NB)    // 2224 real rows
#define MPAD    2240         // 35*64
#define SD      23           // d-slices: max ceil(L/1024)

#define BM      64           // GEMM tile rows (R11-proven)
#define BN      32           // GEMM tile cols

// builder regions (blocks of 256 threads), ~1 element/thread for latency
#define BT_BLOCKS  1920                     // 1024 r x 480 pairs / 256
#define A_BLOCKS   4200                     // 2240 rows x 480 pairs / 256
#define S_BLOCKS   184                      // 23552 t x 2 halves / 256
#define ALL_BLOCKS (BT_BLOCKS + A_BLOCKS + S_BLOCKS)

typedef _Float16 f16x8 __attribute__((ext_vector_type(8)));
typedef float    f32x4 __attribute__((ext_vector_type(4)));

struct alignas(16) CqtArgs {
    unsigned short ct[KP];      // FIRST member, 16B-aligned: col -> k|d<<7|c<<12; 0xFFFF pad
    int   wl[NBINS];            // per-bin window length (descending)
    float omega[NBINS];         // 2*pi*f/SR
    float invL[NBINS];          // 1/wl
    int   Ktot;
};

// ---------------- fused builder: Bt + A + S, fine-grained ---------------------
__global__ __launch_bounds__(256)
void build_all(unsigned short* __restrict__ Am, unsigned short* __restrict__ Bt,
               float* __restrict__ S, const float2* __restrict__ X2, CqtArgs a) {
    const int blk = blockIdx.x;
    const int tid = threadIdx.x;
    const float TWOPI = 6.28318530717958647692f;

    if (blk < BT_BLOCKS) {
        // Bt[r][2j]=cos(w_k t)*hann, [2j+1]=sin(w_k t)*hann; ONE pair per thread
        const int idx = blk * 256 + tid;         // < 1024*480
        const int r   = idx / KPH;
        const int j   = idx - r * KPH;
        unsigned int pack = 0;
        const unsigned short rec = a.ct[2 * j];
        if (rec != 0xFFFFu) {
            const int k = rec & 0x7F, d = (rec >> 7) & 0x1F;
            const int t = (d << 10) + r;
            if (t < a.wl[k]) {
                const float tf = (float)t;
                const float w  = 0.5f - 0.5f * cosf(TWOPI * tf * a.invL[k]);
                float s, c;
                sincosf(a.omega[k] * tf, &s, &c);
                pack = (unsigned int)__half_as_ushort(__float2half(c * w))
                     | ((unsigned int)__half_as_ushort(__float2half(s * w)) << 16);
            }
        }
        *(unsigned int*)(Bt + (size_t)r * KP + 2 * j) = pack;   // coalesced 4B
    } else if (blk < BT_BLOCKS + A_BLOCKS) {
        // A[row=(g*8+b)][2j]=Re X[b,k,g-d], [2j+1]=-Im X[b,k,g-d]; ONE pair/thread
        const int idx = (blk - BT_BLOCKS) * 256 + tid;   // < 2240*480
        const int row = idx / KPH;
        const int j   = idx - row * KPH;
        unsigned int pack = 0;
        const unsigned short rec = a.ct[2 * j];
        if (row < MROWS && rec != 0xFFFFu) {
            const int k = rec & 0x7F, d = (rec >> 7) & 0x1F;
            const int g = row >> 3, b = row & 7;
            const int f = g - d;
            if (f >= 0 && f < NFRAMES) {
                const float2 x = X2[((size_t)b * NBINS + k) * NFRAMES + f];
                pack = (unsigned int)__half_as_ushort(__float2half(x.x))
                     | ((unsigned int)__half_as_ushort(__float2half(-x.y)) << 16);
            }
        }
        *(unsigned int*)(Am + (size_t)row * KP + 2 * j) = pack; // coalesced 4B
    } else {
        // S[t] = sum_k [t < wl_k] hann_k(t)^2 ; TWO lanes per t (k split 0..41/42..83),
        // combined via shfl_xor. wl descending -> break valid within each half.
        const int gid = (blk - BT_BLOCKS - A_BLOCKS) * 256 + tid;  // < 2*23552
        const int t   = gid >> 1;
        const int h   = gid & 1;
        float sum = 0.f;
        const int k0 = h * (NBINS / 2);
        for (int k = k0; k < k0 + NBINS / 2; ++k) {
            if (t >= a.wl[k]) break;
            const float w = 0.5f - 0.5f * cosf(TWOPI * (float)t * a.invL[k]);
            sum += w * w;
        }
        const float tot = sum + __shfl_xor(sum, 1, 64);
        if (h == 0) S[t] = tot;
    }
}

// inverse norm: fixed-bound fully-unrolled MASKED sum (23 independent loads, no
// serial load->add chain). Masked-out terms add exact +0.0f -> bit-identical.
__device__ __forceinline__ float inv_norm(const float* __restrict__ S, int g, int ncol) {
    if (g >= GBLK) return 1.0f;
    const int lo = (g > NFRAMES - 1) ? (g - (NFRAMES - 1)) : 0;
    const int hi = g < (SD - 1) ? g : (SD - 1);
    float s = 0.f;
#pragma unroll
    for (int d = 0; d < SD; ++d) {
        const float v = S[(d << 10) + ncol];
        s += (d >= lo && d <= hi) ? v : 0.0f;
    }
    return (s > 1e-10f) ? 1.0f / s : 1.0f;
}

// GEMM (R11-proven): C[M=2240][N=1024] = A[M][K=960] * Bt[N][K]^T, f16/f32 acc.
// 64x32 tile (1120 blocks), 4 waves (2m x 2n), wave = 32x16 via 2x
// mfma_f32_16x16x32_f16. LDS chunk-XOR swizzle; next-K register prefetch.
__global__ __launch_bounds__(256)
void gemm_icqt(const unsigned short* __restrict__ Am, const unsigned short* __restrict__ Bt,
               const float* __restrict__ S, float* __restrict__ out, int length) {
    __shared__ __align__(16) char lds[12288];     // A: 64x64 f16 = 8KB, B: 32x64 = 4KB
    const int tid = threadIdx.x;
    const int l   = tid & 63;
    const int wid = tid >> 6;
    const int wm  = wid >> 1, wn = wid & 1;
    const int bm  = blockIdx.x, bn = blockIdx.y;

    // A staging: 512 chunks, 2/thread; B staging: 256 chunks, 1/thread
    const int q0 = tid,      q1 = tid + 256;
    const int r0 = q0 >> 3,  c0 = q0 & 7, s0 = c0 ^ (r0 & 7);
    const int r1 = q1 >> 3,  c1 = q1 & 7, s1 = c1 ^ (r1 & 7);
    const int r2 = tid >> 3, c2 = tid & 7, s2 = c2 ^ (r2 & 7);

    const char* gA0 = (const char*)Am + ((size_t)(bm * BM + r0) * KP + s0 * 8) * 2;
    const char* gA1 = (const char*)Am + ((size_t)(bm * BM + r1) * KP + s1 * 8) * 2;
    const char* gB0 = (const char*)Bt + ((size_t)(bn * BN + r2) * KP + s2 * 8) * 2;
    char* lA = lds;
    char* lB = lds + 8192;

    f32x4 acc0 = {0.f,0.f,0.f,0.f}, acc1 = {0.f,0.f,0.f,0.f};

    f16x8 ra0 = *(const f16x8*)(gA0);
    f16x8 ra1 = *(const f16x8*)(gA1);
    f16x8 rb  = *(const f16x8*)(gB0);

    const int arow0 = wm * 32 + (l & 15), arow1 = arow0 + 16;
    const int brow  = wn * 16 + (l & 15);
    const int kq = l >> 4;

    for (int kk = 0; kk < KP; kk += 64) {
        __syncthreads();                     // previous frag reads complete
        *(f16x8*)(lA + q0 * 16) = ra0;
        *(f16x8*)(lA + q1 * 16) = ra1;
        *(f16x8*)(lB + tid * 16) = rb;
        __syncthreads();
        if (kk + 64 < KP) {                  // next-panel loads in MFMA shadow
            ra0 = *(const f16x8*)(gA0 + (kk + 64) * 2);
            ra1 = *(const f16x8*)(gA1 + (kk + 64) * 2);
            rb  = *(const f16x8*)(gB0 + (kk + 64) * 2);
        }
#pragma unroll
        for (int ks = 0; ks < 2; ++ks) {
            const int kb = ks * 4 + kq;
            f16x8 a0 = *(const f16x8*)(lA + arow0 * 128 + ((kb ^ (arow0 & 7)) << 4));
            f16x8 a1 = *(const f16x8*)(lA + arow1 * 128 + ((kb ^ (arow1 & 7)) << 4));
            f16x8 b0 = *(const f16x8*)(lB + brow  * 128 + ((kb ^ (brow  & 7)) << 4));
            acc0 = __builtin_amdgcn_mfma_f32_16x16x32_f16(a0, b0, acc0, 0, 0, 0);
            acc1 = __builtin_amdgcn_mfma_f32_16x16x32_f16(a1, b0, acc1, 0, 0, 0);
        }
    }

    // epilogue: C/D layout col=l&15, row=(l>>4)*4+reg. Per lane: 2 g's, 1 ncol.
    const int mbase = bm * BM + wm * 32;
    const int ncol  = bn * BN + wn * 16 + (l & 15);
    const int g0    = (mbase >> 3) + (kq >> 1);
    const float inv0 = inv_norm(S, g0,     ncol);
    const float inv1 = inv_norm(S, g0 + 2, ncol);

#pragma unroll
    for (int mi = 0; mi < 2; ++mi) {
        const f32x4 v    = mi ? acc1 : acc0;
        const float invv = mi ? inv1 : inv0;
#pragma unroll
        for (int reg = 0; reg < 4; ++reg) {
            const int mrow = mbase + mi * 16 + kq * 4 + reg;
            if (mrow < MROWS) {
                const int g = mrow >> 3, b = mrow & 7;
                const int p = (g << 10) + ncol;
                if (p < length)
                    out[(size_t)b * length + p] = v[reg] * invv;
            }
        }
    }
}

// Last-resort fallback (ws too small): on-the-fly trig gather.
__global__ void icqt_gather_fallback(const float* __restrict__ X, float* __restrict__ out,
                                     CqtArgs a, int length) {
    const int p = blockIdx.x * blockDim.x + threadIdx.x;
    if (p >= length) return;
    float acc[NB];
#pragma unroll
    for (int b = 0; b < NB; ++b) acc[b] = 0.0f;
    float nrm = 0.0f;
    int fhi = p >> 10;
    if (fhi > NFRAMES - 1) fhi = NFRAMES - 1;
    const float2* X2 = reinterpret_cast<const float2*>(X);
    for (int k = 0; k < NBINS; ++k) {
        const int L = a.wl[k];
        int flo = (p - L + HOP) >> 10;
        if (flo < 0) flo = 0;
        for (int f = flo; f <= fhi; ++f) {
            const int t = p - (f << 10);
            if (t < L) {
                float tf = (float)t;
                float ang = a.omega[k] * tf;
                float s = sinf(ang), c = cosf(ang);
                float w = 0.5f - 0.5f * cosf(6.28318530717958647692f * tf * a.invL[k]);
                float bre = c * w, bim = s * w;
                nrm += w * w;
                const int base = k * NFRAMES + f;
#pragma unroll
                for (int b = 0; b < NB; ++b) {
                    float2 cv = X2[(size_t)b * (NBINS * NFRAMES) + base];
                    acc[b] += cv.x * bre - cv.y * bim;
                }
            }
        }
    }
    const float inv = 1.0f / ((nrm > 1e-10f) ? nrm : 1.0f);
#pragma unroll
    for (int b = 0; b < NB; ++b)
        out[(size_t)b * length + p] = acc[b] * inv;
}

extern "C" void kernel_launch(void* const* d_in, const int* in_sizes, int n_in,
                              void* d_out, int out_size, void* d_ws, size_t ws_size,
                              hipStream_t stream) {
    // Host geometry (deterministic; np.round = banker's via nearbyint)
    CqtArgs a;
    int cb[NBINS];
    const double SR = 44100.0;
    const double Q  = 1.0 / (std::exp2(1.0 / 12.0) - 1.0);
    int Ktot = 0;
    for (int k = 0; k < NBINS; ++k) {
        double f = 32.7 * std::exp2((double)k / 12.0);
        int L = (int)std::nearbyint(Q * SR / f);
        a.wl[k]    = L;
        cb[k]      = Ktot;
        a.omega[k] = (float)(2.0 * 3.14159265358979323846 * f / SR);
        a.invL[k]  = (float)(1.0 / (double)L);
        Ktot += 2 * ((L + 1023) / 1024);
    }
    a.Ktot = Ktot;
    for (int col = 0; col < KP; ++col) a.ct[col] = 0xFFFF;
    if (Ktot <= KP) {
        for (int k = 0; k < NBINS; ++k) {
            const int D2 = 2 * ((a.wl[k] + 1023) / 1024);
            for (int j = 0; j < D2; ++j)
                a.ct[cb[k] + j] = (unsigned short)(k | ((j >> 1) << 7) | ((j & 1) << 12));
        }
    }

    const int length = out_size / NB;            // 283800
    const float* X = (const float*)d_in[0];
    float* out     = (float*)d_out;

    // ws layout: [ A f16 MPADxKP ][ Bt f16 1024xKP ][ S f32 23*1024 ]
    const size_t offA = 0;
    const size_t szA  = (size_t)MPAD * KP * 2;           // 4,300,800
    const size_t offB = offA + szA;
    const size_t szB  = (size_t)1024 * KP * 2;           // 1,966,080
    const size_t offS = offB + szB;
    const size_t szS  = (size_t)SD * 1024 * 4;           //    94,208
    const size_t need = offS + szS;

    if (Ktot > KP || a.wl[0] > SD * 1024 || ws_size < need) {
        const int blocks = (length + 255) / 256;
        icqt_gather_fallback<<<blocks, 256, 0, stream>>>(X, out, a, length);
        return;
    }

    unsigned short* Am = (unsigned short*)((char*)d_ws + offA);
    unsigned short* Bt = (unsigned short*)((char*)d_ws + offB);
    float*          S  = (float*)((char*)d_ws + offS);

    build_all<<<dim3(ALL_BLOCKS), 256, 0, stream>>>(Am, Bt, S, (const float2*)X, a);
    gemm_icqt<<<dim3(MPAD / BM, 1024 / BN), 256, 0, stream>>>(Am, Bt, S, out, length);
}

// Round 16
// 43.372 us; speedup vs baseline: 1.7315x; 1.0851x over previous
//
#include <hip/hip_runtime.h>
#include <hip/hip_fp16.h>
#include <cmath>

#define NBINS   84
#define NFRAMES 256
#define HOP     1024
#define NB      8            // nb_samples * nb_channels
#define KP      960          // padded K (f16 columns of A / rows of B)
#define KPH     (KP/2)       // 480 cos/sin column pairs
#define GBLK    278          // number of 1024-sample output blocks
#define MROWS   (GBLK*NB)    // 2224 real rows
#define MPAD    2240         // 35*64
#define SD      23           // d-slices: max ceil(L/1024)

#define BM      64           // GEMM tile rows (R11-proven)
#define BN      32           // GEMM tile cols
#define NT      (KP/64)      // 15 K-tiles
#define TILEB   12288        // one LDS buffer: A 8KB + B 4KB

// builder regions (blocks of 256 threads), ~1 element/thread (R15-proven-neutral)
#define BT_BLOCKS  1920                     // 1024 r x 480 pairs / 256
#define A_BLOCKS   4200                     // 2240 rows x 480 pairs / 256
#define S_BLOCKS   184                      // 23552 t x 2 halves / 256
#define ALL_BLOCKS (BT_BLOCKS + A_BLOCKS + S_BLOCKS)

typedef _Float16 f16x8 __attribute__((ext_vector_type(8)));
typedef float    f32x4 __attribute__((ext_vector_type(4)));

#define VMCNT(N) asm volatile("s_waitcnt vmcnt(" #N ")" ::: "memory")

__device__ __forceinline__ void gload_lds16(const void* g, void* l) {
    __builtin_amdgcn_global_load_lds(
        (__attribute__((address_space(1))) void*)(g),
        (__attribute__((address_space(3))) void*)(l), 16, 0, 0);
}

struct alignas(16) CqtArgs {
    unsigned short ct[KP];      // FIRST member, 16B-aligned: col -> k|d<<7|c<<12; 0xFFFF pad
    int   wl[NBINS];            // per-bin window length (descending)
    float omega[NBINS];         // 2*pi*f/SR
    float invL[NBINS];          // 1/wl
    int   Ktot;
};

// ---------------- fused builder: Bt + A + S, fine-grained ---------------------
__global__ __launch_bounds__(256)
void build_all(unsigned short* __restrict__ Am, unsigned short* __restrict__ Bt,
               float* __restrict__ S, const float2* __restrict__ X2, CqtArgs a) {
    const int blk = blockIdx.x;
    const int tid = threadIdx.x;
    const float TWOPI = 6.28318530717958647692f;

    if (blk < BT_BLOCKS) {
        // Bt[r][2j]=cos(w_k t)*hann, [2j+1]=sin(w_k t)*hann; ONE pair per thread
        const int idx = blk * 256 + tid;         // < 1024*480
        const int r   = idx / KPH;
        const int j   = idx - r * KPH;
        unsigned int pack = 0;
        const unsigned short rec = a.ct[2 * j];
        if (rec != 0xFFFFu) {
            const int k = rec & 0x7F, d = (rec >> 7) & 0x1F;
            const int t = (d << 10) + r;
            if (t < a.wl[k]) {
                const float tf = (float)t;
                const float w  = 0.5f - 0.5f * cosf(TWOPI * tf * a.invL[k]);
                float s, c;
                sincosf(a.omega[k] * tf, &s, &c);
                pack = (unsigned int)__half_as_ushort(__float2half(c * w))
                     | ((unsigned int)__half_as_ushort(__float2half(s * w)) << 16);
            }
        }
        *(unsigned int*)(Bt + (size_t)r * KP + 2 * j) = pack;   // coalesced 4B
    } else if (blk < BT_BLOCKS + A_BLOCKS) {
        // A[row=(g*8+b)][2j]=Re X[b,k,g-d], [2j+1]=-Im X[b,k,g-d]; ONE pair/thread
        const int idx = (blk - BT_BLOCKS) * 256 + tid;   // < 2240*480
        const int row = idx / KPH;
        const int j   = idx - row * KPH;
        unsigned int pack = 0;
        const unsigned short rec = a.ct[2 * j];
        if (row < MROWS && rec != 0xFFFFu) {
            const int k = rec & 0x7F, d = (rec >> 7) & 0x1F;
            const int g = row >> 3, b = row & 7;
            const int f = g - d;
            if (f >= 0 && f < NFRAMES) {
                const float2 x = X2[((size_t)b * NBINS + k) * NFRAMES + f];
                pack = (unsigned int)__half_as_ushort(__float2half(x.x))
                     | ((unsigned int)__half_as_ushort(__float2half(-x.y)) << 16);
            }
        }
        *(unsigned int*)(Am + (size_t)row * KP + 2 * j) = pack; // coalesced 4B
    } else {
        // S[t] = sum_k [t < wl_k] hann_k(t)^2 ; TWO lanes per t, shfl_xor combine
        const int gid = (blk - BT_BLOCKS - A_BLOCKS) * 256 + tid;  // < 2*23552
        const int t   = gid >> 1;
        const int h   = gid & 1;
        float sum = 0.f;
        const int k0 = h * (NBINS / 2);
        for (int k = k0; k < k0 + NBINS / 2; ++k) {
            if (t >= a.wl[k]) break;
            const float w = 0.5f - 0.5f * cosf(TWOPI * (float)t * a.invL[k]);
            sum += w * w;
        }
        const float tot = sum + __shfl_xor(sum, 1, 64);
        if (h == 0) S[t] = tot;
    }
}

// inverse norm: fixed-bound fully-unrolled MASKED sum (bit-identical to bounded sum)
__device__ __forceinline__ float inv_norm(const float* __restrict__ S, int g, int ncol) {
    if (g >= GBLK) return 1.0f;
    const int lo = (g > NFRAMES - 1) ? (g - (NFRAMES - 1)) : 0;
    const int hi = g < (SD - 1) ? g : (SD - 1);
    float s = 0.f;
#pragma unroll
    for (int d = 0; d < SD; ++d) {
        const float v = S[(d << 10) + ncol];
        s += (d >= lo && d <= hi) ? v : 0.0f;
    }
    return (s > 1e-10f) ? 1.0f / s : 1.0f;
}

// GEMM: C[M=2240][N=1024] = A[M][K=960] * Bt[N][K]^T, f16/f32 acc.
// 64x32 tile, 4 waves. Staging via double-buffered global_load_lds (LDS dest
// linear tid*16, XOR swizzle pre-applied to GLOBAL source) with COUNTED
// vmcnt(3) waits + raw s_barrier -- next tile's loads stay in flight across
// the barrier (no vmcnt(0) drain). 1D grid, bijective XCD swizzle (1120=8*140,
// bm-chunk per XCD: per-XCD panel footprint ~2.6MB < 4MB L2).
__global__ __launch_bounds__(256)
void gemm_icqt(const unsigned short* __restrict__ Am, const unsigned short* __restrict__ Bt,
               const float* __restrict__ S, float* __restrict__ out, int length) {
    __shared__ __align__(16) char lds[2 * TILEB];     // 24 KB: 2 x (A 8KB + B 4KB)
    const int tid = threadIdx.x;
    const int l   = tid & 63;
    const int wid = tid >> 6;
    const int wm  = wid >> 1, wn = wid & 1;

    const int bid = blockIdx.x;
    const int swz = (bid & 7) * 140 + (bid >> 3);     // XCD-chunked, bijective
    const int bm  = swz >> 5;                         // 0..34
    const int bn  = swz & 31;                         // 0..31

    // staging geometry: A 512 chunks (2/thread: q0=tid, q1=tid+256), B 256 (1/thread)
    const int q0 = tid,      q1 = tid + 256;
    const int r0 = q0 >> 3,  c0 = q0 & 7, s0 = c0 ^ (r0 & 7);
    const int r1 = q1 >> 3,  c1 = q1 & 7, s1 = c1 ^ (r1 & 7);
    const int r2 = tid >> 3, c2 = tid & 7, s2 = c2 ^ (r2 & 7);

    const char* gA0 = (const char*)Am + ((size_t)(bm * BM + r0) * KP + s0 * 8) * 2;
    const char* gA1 = (const char*)Am + ((size_t)(bm * BM + r1) * KP + s1 * 8) * 2;
    const char* gB0 = (const char*)Bt + ((size_t)(bn * BN + r2) * KP + s2 * 8) * 2;

    f32x4 acc0 = {0.f,0.f,0.f,0.f}, acc1 = {0.f,0.f,0.f,0.f};

    const int arow0 = wm * 32 + (l & 15), arow1 = arow0 + 16;
    const int brow  = wn * 16 + (l & 15);
    const int kq = l >> 4;

    // prologue: tiles 0,1 -> buffers 0,1 (6 loads/thread in flight)
    {
        char* bA = lds;            char* bB = lds + 8192;
        gload_lds16(gA0,       bA + tid * 16);
        gload_lds16(gA1,       bA + 4096 + tid * 16);
        gload_lds16(gB0,       bB + tid * 16);
        char* cA = lds + TILEB;    char* cB = cA + 8192;
        gload_lds16(gA0 + 128, cA + tid * 16);
        gload_lds16(gA1 + 128, cA + 4096 + tid * 16);
        gload_lds16(gB0 + 128, cB + tid * 16);
    }

#pragma unroll
    for (int t = 0; t < NT; ++t) {
        char* bA = lds + (t & 1) * TILEB;
        char* bB = bA + 8192;
        if (t + 1 < NT) { VMCNT(3); } else { VMCNT(0); }   // static after unroll
        __builtin_amdgcn_s_barrier();                      // raw: no vmcnt(0) drain
#pragma unroll
        for (int ks = 0; ks < 2; ++ks) {
            const int kb = ks * 4 + kq;
            f16x8 a0 = *(const f16x8*)(bA + arow0 * 128 + ((kb ^ (arow0 & 7)) << 4));
            f16x8 a1 = *(const f16x8*)(bA + arow1 * 128 + ((kb ^ (arow1 & 7)) << 4));
            f16x8 b0 = *(const f16x8*)(bB + brow  * 128 + ((kb ^ (brow  & 7)) << 4));
            acc0 = __builtin_amdgcn_mfma_f32_16x16x32_f16(a0, b0, acc0, 0, 0, 0);
            acc1 = __builtin_amdgcn_mfma_f32_16x16x32_f16(a1, b0, acc1, 0, 0, 0);
        }
        if (t + 2 < NT) {
            __builtin_amdgcn_s_barrier();                  // all waves done reading bA/bB
            const int off = (t + 2) * 128;                 // 64 cols * 2B per tile
            gload_lds16(gA0 + off, bA + tid * 16);
            gload_lds16(gA1 + off, bA + 4096 + tid * 16);
            gload_lds16(gB0 + off, bB + tid * 16);
        }
    }

    // epilogue: C/D layout col=l&15, row=(l>>4)*4+reg. Per lane: 2 g's, 1 ncol.
    const int mbase = bm * BM + wm * 32;
    const int ncol  = bn * BN + wn * 16 + (l & 15);
    const int g0    = (mbase >> 3) + (kq >> 1);
    const float inv0 = inv_norm(S, g0,     ncol);
    const float inv1 = inv_norm(S, g0 + 2, ncol);

#pragma unroll
    for (int mi = 0; mi < 2; ++mi) {
        const f32x4 v    = mi ? acc1 : acc0;
        const float invv = mi ? inv1 : inv0;
#pragma unroll
        for (int reg = 0; reg < 4; ++reg) {
            const int mrow = mbase + mi * 16 + kq * 4 + reg;
            if (mrow < MROWS) {
                const int g = mrow >> 3, b = mrow & 7;
                const int p = (g << 10) + ncol;
                if (p < length)
                    out[(size_t)b * length + p] = v[reg] * invv;
            }
        }
    }
}

// Last-resort fallback (ws too small): on-the-fly trig gather.
__global__ void icqt_gather_fallback(const float* __restrict__ X, float* __restrict__ out,
                                     CqtArgs a, int length) {
    const int p = blockIdx.x * blockDim.x + threadIdx.x;
    if (p >= length) return;
    float acc[NB];
#pragma unroll
    for (int b = 0; b < NB; ++b) acc[b] = 0.0f;
    float nrm = 0.0f;
    int fhi = p >> 10;
    if (fhi > NFRAMES - 1) fhi = NFRAMES - 1;
    const float2* X2 = reinterpret_cast<const float2*>(X);
    for (int k = 0; k < NBINS; ++k) {
        const int L = a.wl[k];
        int flo = (p - L + HOP) >> 10;
        if (flo < 0) flo = 0;
        for (int f = flo; f <= fhi; ++f) {
            const int t = p - (f << 10);
            if (t < L) {
                float tf = (float)t;
                float ang = a.omega[k] * tf;
                float s = sinf(ang), c = cosf(ang);
                float w = 0.5f - 0.5f * cosf(6.28318530717958647692f * tf * a.invL[k]);
                float bre = c * w, bim = s * w;
                nrm += w * w;
                const int base = k * NFRAMES + f;
#pragma unroll
                for (int b = 0; b < NB; ++b) {
                    float2 cv = X2[(size_t)b * (NBINS * NFRAMES) + base];
                    acc[b] += cv.x * bre - cv.y * bim;
                }
            }
        }
    }
    const float inv = 1.0f / ((nrm > 1e-10f) ? nrm : 1.0f);
#pragma unroll
    for (int b = 0; b < NB; ++b)
        out[(size_t)b * length + p] = acc[b] * inv;
}

extern "C" void kernel_launch(void* const* d_in, const int* in_sizes, int n_in,
                              void* d_out, int out_size, void* d_ws, size_t ws_size,
                              hipStream_t stream) {
    // Host geometry (deterministic; np.round = banker's via nearbyint)
    CqtArgs a;
    int cb[NBINS];
    const double SR = 44100.0;
    const double Q  = 1.0 / (std::exp2(1.0 / 12.0) - 1.0);
    int Ktot = 0;
    for (int k = 0; k < NBINS; ++k) {
        double f = 32.7 * std::exp2((double)k / 12.0);
        int L = (int)std::nearbyint(Q * SR / f);
        a.wl[k]    = L;
        cb[k]      = Ktot;
        a.omega[k] = (float)(2.0 * 3.14159265358979323846 * f / SR);
        a.invL[k]  = (float)(1.0 / (double)L);
        Ktot += 2 * ((L + 1023) / 1024);
    }
    a.Ktot = Ktot;
    for (int col = 0; col < KP; ++col) a.ct[col] = 0xFFFF;
    if (Ktot <= KP) {
        for (int k = 0; k < NBINS; ++k) {
            const int D2 = 2 * ((a.wl[k] + 1023) / 1024);
            for (int j = 0; j < D2; ++j)
                a.ct[cb[k] + j] = (unsigned short)(k | ((j >> 1) << 7) | ((j & 1) << 12));
        }
    }

    const int length = out_size / NB;            // 283800
    const float* X = (const float*)d_in[0];
    float* out     = (float*)d_out;

    // ws layout: [ A f16 MPADxKP ][ Bt f16 1024xKP ][ S f32 23*1024 ]
    const size_t offA = 0;
    const size_t szA  = (size_t)MPAD * KP * 2;           // 4,300,800
    const size_t offB = offA + szA;
    const size_t szB  = (size_t)1024 * KP * 2;           // 1,966,080
    const size_t offS = offB + szB;
    const size_t szS  = (size_t)SD * 1024 * 4;           //    94,208
    const size_t need = offS + szS;

    if (Ktot > KP || a.wl[0] > SD * 1024 || ws_size < need) {
        const int blocks = (length + 255) / 256;
        icqt_gather_fallback<<<blocks, 256, 0, stream>>>(X, out, a, length);
        return;
    }

    unsigned short* Am = (unsigned short*)((char*)d_ws + offA);
    unsigned short* Bt = (unsigned short*)((char*)d_ws + offB);
    float*          S  = (float*)((char*)d_ws + offS);

    build_all<<<dim3(ALL_BLOCKS), 256, 0, stream>>>(Am, Bt, S, (const float2*)X, a);
    gemm_icqt<<<dim3((MPAD / BM) * (1024 / BN)), 256, 0, stream>>>(Am, Bt, S, out, length);
}